// Round 2
// baseline (1086.862 us; speedup 1.0000x reference)
//
#include <hip/hip_runtime.h>
#include <math.h>

#define N_NODES 50000
#define N_EDGES 800000
#define IN_C    256
#define HID     96
#define OUT_C   64
#define NLAYER  3

// ---------------- CSR build ----------------
// NOTE: harness passes integer inputs as int32 (NOT int64 like the reference).

__global__ void k_init(int* cnt, int* cur, int* counter, int n) {
    int v = blockIdx.x * blockDim.x + threadIdx.x;
    if (v < n) { cnt[v] = 0; cur[v] = 0; }
    if (v == 0) *counter = 0;
}

__global__ void k_count(const int* __restrict__ ei, int* cnt, int e) {
    int i = blockIdx.x * blockDim.x + threadIdx.x;
    if (i < e) {
        int d = ei[e + i];   // row 1 = dst
        atomicAdd(&cnt[d], 1);
    }
}

__global__ void k_node(const int* __restrict__ cnt, float* __restrict__ dis,
                       int* __restrict__ start, int* counter, int n) {
    int v = blockIdx.x * blockDim.x + threadIdx.x;
    if (v < n) {
        int c = cnt[v];
        // deg includes self-loop, always >= 1
        dis[v] = (float)(1.0 / sqrt((double)(c + 1)));
        start[v] = atomicAdd(counter, c);
    }
}

__global__ void k_fill(const int* __restrict__ ei, const float* __restrict__ dis,
                       const int* __restrict__ start, int* __restrict__ cur,
                       int* __restrict__ col, float* __restrict__ wgt, int e) {
    int i = blockIdx.x * blockDim.x + threadIdx.x;
    if (i < e) {
        int s = ei[i];
        int d = ei[e + i];
        int slot = start[d] + atomicAdd(&cur[d], 1);
        col[slot] = s;
        wgt[slot] = dis[s] * dis[d];
    }
}

// ---------------- h0 = x @ proj_w + proj_b (two K=128 passes) ----------------

__global__ __launch_bounds__(384) void k_h0(const float* __restrict__ x,
                                            const float* __restrict__ W,
                                            const float* __restrict__ bias,
                                            float* __restrict__ h0,
                                            int k0, int final_pass) {
    __shared__ float Ws[128 * HID];   // 48 KB
    __shared__ float xs[4][128];
    int tx = threadIdx.x, ty = threadIdx.y;
    int t = ty * HID + tx;
    for (int i = t; i < 128 * HID; i += 384) Ws[i] = W[k0 * HID + i];
    __syncthreads();
    const int ng = N_NODES / 4;
    for (int g = blockIdx.x; g < ng; g += gridDim.x) {
        int r = g * 4 + ty;
        for (int i = tx; i < 128; i += HID) xs[ty][i] = x[r * IN_C + k0 + i];
        __syncthreads();
        float a = 0.f;
        #pragma unroll 16
        for (int i = 0; i < 128; i++) a = fmaf(xs[ty][i], Ws[i * HID + tx], a);
        if (final_pass)
            h0[r * HID + tx] = h0[r * HID + tx] + a + bias[tx];
        else
            h0[r * HID + tx] = a;
        __syncthreads();
    }
}

// ---------------- per-layer: m = quantize(h) @ conv_w[k] ----------------

__global__ __launch_bounds__(384) void k_conv(const float* __restrict__ h,
                                              const float* __restrict__ bn,
                                              const float* __restrict__ W,
                                              float delta, float inv_delta,
                                              float* __restrict__ m) {
    __shared__ float Ws[HID * HID];   // 36 KB
    __shared__ float hq[4][HID];
    int tx = threadIdx.x, ty = threadIdx.y;
    int t = ty * HID + tx;
    for (int i = t; i < HID * HID; i += 384) Ws[i] = W[i];
    __syncthreads();
    const int ng = N_NODES / 4;
    for (int g = blockIdx.x; g < ng; g += gridDim.x) {
        int r = g * 4 + ty;
        float hv = h[r * HID + tx];
        float bv = bn[r * HID + tx] * delta;            // exact (delta = 2^-k)
        hq[ty][tx] = floorf((hv + bv) * inv_delta) * delta - bv;
        __syncthreads();
        float a = 0.f;
        #pragma unroll 16
        for (int i = 0; i < HID; i++) a = fmaf(hq[ty][i], Ws[i * HID + tx], a);
        m[r * HID + tx] = a;
        __syncthreads();
    }
}

// ---------------- per-layer: h = relu(segment_sum + conv_b + eps) ----------------

__global__ __launch_bounds__(384) void k_agg(const float* __restrict__ m,
                                             const int* __restrict__ col,
                                             const float* __restrict__ wgt,
                                             const int* __restrict__ start,
                                             const int* __restrict__ cnt,
                                             const float* __restrict__ dis,
                                             const float* __restrict__ cb,
                                             const float* __restrict__ eps,
                                             float* __restrict__ hout) {
    int tx = threadIdx.x;
    int d = blockIdx.x * 4 + threadIdx.y;
    if (d >= N_NODES) return;
    int s0 = start[d], c = cnt[d];
    float a = 0.f;
    for (int e = 0; e < c; e++) {
        int s = col[s0 + e];
        a = fmaf(m[s * HID + tx], wgt[s0 + e], a);
    }
    float dv = dis[d];
    a = fmaf(m[d * HID + tx], dv * dv, a);   // self-loop
    a += cb[tx] + eps[d * HID + tx];
    hout[d * HID + tx] = fmaxf(a, 0.f);
}

// ---------------- out = concat(h0, h) @ out_w + out_b ----------------

__global__ __launch_bounds__(256) void k_out(const float* __restrict__ h0,
                                             const float* __restrict__ h,
                                             const float* __restrict__ W,
                                             const float* __restrict__ bias,
                                             float* __restrict__ out) {
    __shared__ float Ws[2 * HID * OUT_C];   // 48 KB
    __shared__ float cs[4][2 * HID];
    int tx = threadIdx.x, ty = threadIdx.y;
    int t = ty * OUT_C + tx;
    for (int i = t; i < 2 * HID * OUT_C; i += 256) Ws[i] = W[i];
    __syncthreads();
    const int ng = N_NODES / 4;
    for (int g = blockIdx.x; g < ng; g += gridDim.x) {
        int r = g * 4 + ty;
        for (int i = tx; i < HID; i += OUT_C) {
            cs[ty][i] = h0[r * HID + i];
            cs[ty][HID + i] = h[r * HID + i];
        }
        __syncthreads();
        float a = 0.f;
        #pragma unroll 16
        for (int i = 0; i < 2 * HID; i++) a = fmaf(cs[ty][i], Ws[i * OUT_C + tx], a);
        out[r * OUT_C + tx] = a + bias[tx];
        __syncthreads();
    }
}

// ---------------- launch ----------------

extern "C" void kernel_launch(void* const* d_in, const int* in_sizes, int n_in,
                              void* d_out, int out_size, void* d_ws, size_t ws_size,
                              hipStream_t stream) {
    (void)in_sizes; (void)n_in; (void)out_size; (void)ws_size;
    const float* x       = (const float*)d_in[0];
    const int*   ei      = (const int*)d_in[1];     // int32 per harness convention
    const float* proj_w  = (const float*)d_in[2];
    const float* proj_b  = (const float*)d_in[3];
    const float* conv_w  = (const float*)d_in[4];
    const float* conv_b  = (const float*)d_in[5];
    const float* out_w   = (const float*)d_in[6];
    const float* out_b   = (const float*)d_in[7];
    const float* b_noise = (const float*)d_in[8];
    const float* eps_n   = (const float*)d_in[9];
    float*       out     = (float*)d_out;

    char* w = (char*)d_ws;
    size_t off = 0;
    auto alloc = [&](size_t bytes) -> char* {
        char* p = w + off;
        off = (off + bytes + 255) & ~(size_t)255;
        return p;
    };
    float* h0b   = (float*)alloc((size_t)N_NODES * HID * 4);
    float* hA    = (float*)alloc((size_t)N_NODES * HID * 4);   // h ping (aliased in place across layers)
    float* mb    = (float*)alloc((size_t)N_NODES * HID * 4);
    float* dis   = (float*)alloc((size_t)N_NODES * 4);
    float* wgt   = (float*)alloc((size_t)N_EDGES * 4);
    int*   col   = (int*)  alloc((size_t)N_EDGES * 4);
    int*   cnt   = (int*)  alloc((size_t)N_NODES * 4);
    int*   cur   = (int*)  alloc((size_t)N_NODES * 4);
    int*   start = (int*)  alloc((size_t)N_NODES * 4);
    int*   ctr   = (int*)  alloc(256);

    // CSR build (per call; ws is re-poisoned each launch)
    k_init <<<(N_NODES + 255) / 256, 256, 0, stream>>>(cnt, cur, ctr, N_NODES);
    k_count<<<(N_EDGES + 255) / 256, 256, 0, stream>>>(ei, cnt, N_EDGES);
    k_node <<<(N_NODES + 255) / 256, 256, 0, stream>>>(cnt, dis, start, ctr, N_NODES);
    k_fill <<<(N_EDGES + 255) / 256, 256, 0, stream>>>(ei, dis, start, cur, col, wgt, N_EDGES);

    // h0 = x @ proj_w + proj_b  (two K=128 passes)
    dim3 b96(96, 4);
    k_h0<<<1024, b96, 0, stream>>>(x, proj_w, proj_b, h0b, 0, 0);
    k_h0<<<1024, b96, 0, stream>>>(x, proj_w, proj_b, h0b, 128, 1);

    const float deltas[NLAYER] = {1.0f, 0.5f, 0.25f};
    const float* hprev = h0b;
    for (int k = 0; k < NLAYER; k++) {
        float dlt = deltas[k];
        k_conv<<<1280, b96, 0, stream>>>(hprev,
                                         b_noise + (size_t)k * N_NODES * HID,
                                         conv_w + (size_t)k * HID * HID,
                                         dlt, 1.0f / dlt, mb);
        // k_agg reads only mb (+ edge data), so writing hA in place is safe
        k_agg<<<N_NODES / 4, b96, 0, stream>>>(mb, col, wgt, start, cnt, dis,
                                               conv_b + (size_t)k * HID,
                                               eps_n + (size_t)k * N_NODES * HID,
                                               hA);
        hprev = hA;
    }

    dim3 b64(64, 4);
    k_out<<<1024, b64, 0, stream>>>(h0b, hprev, out_w, out_b, out);
}

// Round 3
// 714.979 us; speedup vs baseline: 1.5201x; 1.5201x over previous
//
#include <hip/hip_runtime.h>
#include <math.h>

#define N_NODES 50000
#define N_EDGES 800000
#define IN_C    256
#define HID     96
#define OUT_C   64
#define NLAYER  3
#define KC      96      // K-chunk for k_gemm (LDS W tile rows)
#define XSP     100     // xs row stride in floats (pad breaks stride-96 bank collide)

// ---------------- CSR build ----------------
// NOTE: harness passes integer inputs as int32.

__global__ void k_init(int* cnt, int* cur, int* counter,
                       int* col, float* wgt, int n) {
    int v = blockIdx.x * blockDim.x + threadIdx.x;
    if (v < n) { cnt[v] = 0; cur[v] = 0; }
    if (v == 0) *counter = 0;
    if (v < 8) { col[N_EDGES + v] = 0; wgt[N_EDGES + v] = 0.f; }  // pad for unroll-8 overread
}

__global__ void k_count(const int* __restrict__ ei, int* cnt, int e) {
    int i = blockIdx.x * blockDim.x + threadIdx.x;
    if (i < e) atomicAdd(&cnt[ei[e + i]], 1);   // row 1 = dst
}

__global__ void k_node(const int* __restrict__ cnt, float* __restrict__ dis,
                       int* __restrict__ start, int* counter, int n) {
    int v = blockIdx.x * blockDim.x + threadIdx.x;
    if (v < n) {
        int c = cnt[v];
        dis[v] = (float)(1.0 / sqrt((double)(c + 1)));  // deg incl self-loop >= 1
        start[v] = atomicAdd(counter, c);
    }
}

__global__ void k_fill(const int* __restrict__ ei, const float* __restrict__ dis,
                       const int* __restrict__ start, int* __restrict__ cur,
                       int* __restrict__ col, float* __restrict__ wgt, int e) {
    int i = blockIdx.x * blockDim.x + threadIdx.x;
    if (i < e) {
        int s = ei[i];
        int d = ei[e + i];
        int slot = start[d] + atomicAdd(&cur[d], 1);
        col[slot] = s;
        wgt[slot] = dis[s] * dis[d];
    }
}

// ---------------- generic dense: C[N x 96] = f(A[N x K]) @ W[K x 96] (+bias) ----
// block 384 = 24 og-groups x 16 rg-groups; per-thread tile 4 nodes x 4 outputs;
// 64 nodes per block-group; all LDS reads are ds_read_b128.

template<bool QUANT, bool BIAS>
__global__ __launch_bounds__(384) void k_gemm(
    const float* __restrict__ A, int lda, int K,
    const float* __restrict__ bn, float delta, float inv_delta,
    const float* __restrict__ W, const float* __restrict__ bias,
    float* __restrict__ C)
{
    __shared__ float Ws[KC * HID];      // 36 KB
    __shared__ float xs[64 * XSP];      // 25.6 KB
    const int t  = threadIdx.x;
    const int og = t % 24;              // outputs 4og..4og+3
    const int rg = t / 24;              // nodes 4rg..4rg+3 (within group)
    const int nch = (K + KC - 1) / KC;
    const int ngroups = (N_NODES + 63) / 64;

    float4 bv = make_float4(0.f, 0.f, 0.f, 0.f);
    if (BIAS) bv = *(const float4*)&bias[4 * og];

    for (int g = blockIdx.x; g < ngroups; g += gridDim.x) {
        float acc[4][4];
        #pragma unroll
        for (int r = 0; r < 4; r++)
            #pragma unroll
            for (int o = 0; o < 4; o++) acc[r][o] = 0.f;

        for (int ch = 0; ch < nch; ch++) {
            const int kc0 = ch * KC;
            const int kcw = (K - kc0 < KC) ? (K - kc0) : KC;
            __syncthreads();
            // stage W rows [kc0, kc0+kcw)
            for (int i = t; i < 24 * kcw; i += 384) {
                int k = i / 24, oq = i - k * 24;
                *(float4*)&Ws[k * HID + 4 * oq] =
                    *(const float4*)&W[(size_t)(kc0 + k) * HID + 4 * oq];
            }
            // stage 64 node rows (quantize on the fly if QUANT)
            const int kq4 = kcw >> 2;     // 24 or 16
            const int tot = 64 * kq4;
            for (int i = t; i < tot; i += 384) {
                int node, kq;
                if (kq4 == 24) { node = i / 24; kq = i - node * 24; }
                else           { node = i >> 4; kq = i & 15; }
                int gn = g * 64 + node;
                float4 v = make_float4(0.f, 0.f, 0.f, 0.f);
                if (gn < N_NODES) {
                    v = *(const float4*)&A[(size_t)gn * lda + kc0 + 4 * kq];
                    if (QUANT) {
                        float4 b = *(const float4*)&bn[(size_t)gn * HID + kc0 + 4 * kq];
                        float bx = b.x * delta, by = b.y * delta;
                        float bz = b.z * delta, bw = b.w * delta;
                        v.x = floorf((v.x + bx) * inv_delta) * delta - bx;
                        v.y = floorf((v.y + by) * inv_delta) * delta - by;
                        v.z = floorf((v.z + bz) * inv_delta) * delta - bz;
                        v.w = floorf((v.w + bw) * inv_delta) * delta - bw;
                    }
                }
                *(float4*)&xs[node * XSP + 4 * kq] = v;
            }
            __syncthreads();
            // compute: per 4-k block: 4+4 ds_read_b128, 64 FMA
            for (int k = 0; k < kcw; k += 4) {
                float4 w0 = *(const float4*)&Ws[(k + 0) * HID + 4 * og];
                float4 w1 = *(const float4*)&Ws[(k + 1) * HID + 4 * og];
                float4 w2 = *(const float4*)&Ws[(k + 2) * HID + 4 * og];
                float4 w3 = *(const float4*)&Ws[(k + 3) * HID + 4 * og];
                #pragma unroll
                for (int r = 0; r < 4; r++) {
                    float4 xv = *(const float4*)&xs[(4 * rg + r) * XSP + k];
                    acc[r][0] = fmaf(xv.x, w0.x, acc[r][0]);
                    acc[r][1] = fmaf(xv.x, w0.y, acc[r][1]);
                    acc[r][2] = fmaf(xv.x, w0.z, acc[r][2]);
                    acc[r][3] = fmaf(xv.x, w0.w, acc[r][3]);
                    acc[r][0] = fmaf(xv.y, w1.x, acc[r][0]);
                    acc[r][1] = fmaf(xv.y, w1.y, acc[r][1]);
                    acc[r][2] = fmaf(xv.y, w1.z, acc[r][2]);
                    acc[r][3] = fmaf(xv.y, w1.w, acc[r][3]);
                    acc[r][0] = fmaf(xv.z, w2.x, acc[r][0]);
                    acc[r][1] = fmaf(xv.z, w2.y, acc[r][1]);
                    acc[r][2] = fmaf(xv.z, w2.z, acc[r][2]);
                    acc[r][3] = fmaf(xv.z, w2.w, acc[r][3]);
                    acc[r][0] = fmaf(xv.w, w3.x, acc[r][0]);
                    acc[r][1] = fmaf(xv.w, w3.y, acc[r][1]);
                    acc[r][2] = fmaf(xv.w, w3.z, acc[r][2]);
                    acc[r][3] = fmaf(xv.w, w3.w, acc[r][3]);
                }
            }
        }
        // epilogue
        #pragma unroll
        for (int r = 0; r < 4; r++) {
            int gn = g * 64 + 4 * rg + r;
            if (gn < N_NODES) {
                float4 c;
                c.x = acc[r][0] + bv.x;
                c.y = acc[r][1] + bv.y;
                c.z = acc[r][2] + bv.z;
                c.w = acc[r][3] + bv.w;
                *(float4*)&C[(size_t)gn * HID + 4 * og] = c;
            }
        }
    }
}

// ---------------- per-layer: h = relu(segment_sum + conv_b + eps) ----------------
// unroll-8: 8 independent gathers in flight per thread (latency fix)

__global__ __launch_bounds__(384) void k_agg(const float* __restrict__ m,
                                             const int* __restrict__ col,
                                             const float* __restrict__ wgt,
                                             const int* __restrict__ start,
                                             const int* __restrict__ cnt,
                                             const float* __restrict__ dis,
                                             const float* __restrict__ cb,
                                             const float* __restrict__ eps,
                                             float* __restrict__ hout) {
    const int tx = threadIdx.x;
    const int d = blockIdx.x * 4 + threadIdx.y;   // 12500*4 == N_NODES exactly
    const int s0 = start[d], c = cnt[d];
    const float* mt = m + tx;
    float a0 = 0.f, a1 = 0.f, a2 = 0.f, a3 = 0.f;
    float a4 = 0.f, a5 = 0.f, a6 = 0.f, a7 = 0.f;
    for (int e = 0; e < c; e += 8) {
        int i0 = col[s0 + e + 0]; float w0 = (e + 0 < c) ? wgt[s0 + e + 0] : 0.f;
        int i1 = col[s0 + e + 1]; float w1 = (e + 1 < c) ? wgt[s0 + e + 1] : 0.f;
        int i2 = col[s0 + e + 2]; float w2 = (e + 2 < c) ? wgt[s0 + e + 2] : 0.f;
        int i3 = col[s0 + e + 3]; float w3 = (e + 3 < c) ? wgt[s0 + e + 3] : 0.f;
        int i4 = col[s0 + e + 4]; float w4 = (e + 4 < c) ? wgt[s0 + e + 4] : 0.f;
        int i5 = col[s0 + e + 5]; float w5 = (e + 5 < c) ? wgt[s0 + e + 5] : 0.f;
        int i6 = col[s0 + e + 6]; float w6 = (e + 6 < c) ? wgt[s0 + e + 6] : 0.f;
        int i7 = col[s0 + e + 7]; float w7 = (e + 7 < c) ? wgt[s0 + e + 7] : 0.f;
        a0 = fmaf(mt[i0 * HID], w0, a0);
        a1 = fmaf(mt[i1 * HID], w1, a1);
        a2 = fmaf(mt[i2 * HID], w2, a2);
        a3 = fmaf(mt[i3 * HID], w3, a3);
        a4 = fmaf(mt[i4 * HID], w4, a4);
        a5 = fmaf(mt[i5 * HID], w5, a5);
        a6 = fmaf(mt[i6 * HID], w6, a6);
        a7 = fmaf(mt[i7 * HID], w7, a7);
    }
    float dv = dis[d];
    float a = ((a0 + a1) + (a2 + a3)) + ((a4 + a5) + (a6 + a7));
    a = fmaf(mt[d * HID], dv * dv, a);            // self-loop
    a += cb[tx] + eps[(size_t)d * HID + tx];
    hout[(size_t)d * HID + tx] = fmaxf(a, 0.f);
}

// ---------------- out = concat(h0, h) @ out_w + out_b ----------------

__global__ __launch_bounds__(256) void k_out(const float* __restrict__ h0,
                                             const float* __restrict__ h,
                                             const float* __restrict__ W,
                                             const float* __restrict__ bias,
                                             float* __restrict__ out) {
    __shared__ float Ws[2 * HID * OUT_C];   // 48 KB
    __shared__ float cs[4][2 * HID];
    int tx = threadIdx.x, ty = threadIdx.y;
    int t = ty * OUT_C + tx;
    for (int i = t; i < 2 * HID * OUT_C; i += 256) Ws[i] = W[i];
    __syncthreads();
    const int ng = N_NODES / 4;
    for (int g = blockIdx.x; g < ng; g += gridDim.x) {
        int r = g * 4 + ty;
        for (int i = tx; i < HID; i += OUT_C) {
            cs[ty][i] = h0[r * HID + i];
            cs[ty][HID + i] = h[r * HID + i];
        }
        __syncthreads();
        float a = 0.f;
        #pragma unroll 16
        for (int i = 0; i < 2 * HID; i++) a = fmaf(cs[ty][i], Ws[i * OUT_C + tx], a);
        out[r * OUT_C + tx] = a + bias[tx];
        __syncthreads();
    }
}

// ---------------- launch ----------------

extern "C" void kernel_launch(void* const* d_in, const int* in_sizes, int n_in,
                              void* d_out, int out_size, void* d_ws, size_t ws_size,
                              hipStream_t stream) {
    (void)in_sizes; (void)n_in; (void)out_size; (void)ws_size;
    const float* x       = (const float*)d_in[0];
    const int*   ei      = (const int*)d_in[1];     // int32 per harness convention
    const float* proj_w  = (const float*)d_in[2];
    const float* proj_b  = (const float*)d_in[3];
    const float* conv_w  = (const float*)d_in[4];
    const float* conv_b  = (const float*)d_in[5];
    const float* out_w   = (const float*)d_in[6];
    const float* out_b   = (const float*)d_in[7];
    const float* b_noise = (const float*)d_in[8];
    const float* eps_n   = (const float*)d_in[9];
    float*       out     = (float*)d_out;

    char* w = (char*)d_ws;
    size_t off = 0;
    auto alloc = [&](size_t bytes) -> char* {
        char* p = w + off;
        off = (off + bytes + 255) & ~(size_t)255;
        return p;
    };
    float* h0b   = (float*)alloc((size_t)N_NODES * HID * 4);
    float* hA    = (float*)alloc((size_t)N_NODES * HID * 4);
    float* mb    = (float*)alloc((size_t)N_NODES * HID * 4);
    float* dis   = (float*)alloc((size_t)N_NODES * 4);
    float* wgt   = (float*)alloc((size_t)(N_EDGES + 8) * 4);
    int*   col   = (int*)  alloc((size_t)(N_EDGES + 8) * 4);
    int*   cnt   = (int*)  alloc((size_t)N_NODES * 4);
    int*   cur   = (int*)  alloc((size_t)N_NODES * 4);
    int*   start = (int*)  alloc((size_t)N_NODES * 4);
    int*   ctr   = (int*)  alloc(256);

    // CSR build
    k_init <<<(N_NODES + 255) / 256, 256, 0, stream>>>(cnt, cur, ctr, col, wgt, N_NODES);
    k_count<<<(N_EDGES + 255) / 256, 256, 0, stream>>>(ei, cnt, N_EDGES);
    k_node <<<(N_NODES + 255) / 256, 256, 0, stream>>>(cnt, dis, start, ctr, N_NODES);
    k_fill <<<(N_EDGES + 255) / 256, 256, 0, stream>>>(ei, dis, start, cur, col, wgt, N_EDGES);

    const int ngroups = (N_NODES + 63) / 64;    // 782

    // h0 = x @ proj_w + proj_b (single kernel, K chunked 96+96+64)
    k_gemm<false, true><<<ngroups, 384, 0, stream>>>(
        x, IN_C, IN_C, nullptr, 1.f, 1.f, proj_w, proj_b, h0b);

    const float deltas[NLAYER] = {1.0f, 0.5f, 0.25f};
    const float* hprev = h0b;
    for (int k = 0; k < NLAYER; k++) {
        float dlt = deltas[k];
        // m = quantize(h) @ conv_w[k]
        k_gemm<true, false><<<ngroups, 384, 0, stream>>>(
            hprev, HID, HID,
            b_noise + (size_t)k * N_NODES * HID, dlt, 1.0f / dlt,
            conv_w + (size_t)k * HID * HID, nullptr, mb);
        // h = relu(segment_sum(m) + conv_b + eps)   (reads only mb -> in-place hA ok)
        k_agg<<<N_NODES / 4, dim3(96, 4), 0, stream>>>(
            mb, col, wgt, start, cnt, dis,
            conv_b + (size_t)k * HID,
            eps_n + (size_t)k * N_NODES * HID, hA);
        hprev = hA;
    }

    k_out<<<1024, dim3(64, 4), 0, stream>>>(h0b, hprev, out_w, out_b, out);
}